// Round 20
// baseline (50.445 us; speedup 1.0000x reference)
//
#include <hip/hip_runtime.h>

#define EPSLN 1e-5f

typedef short bf16x8 __attribute__((ext_vector_type(8)));
typedef float f32x4 __attribute__((ext_vector_type(4)));
typedef unsigned short u16;
typedef unsigned short u16x8 __attribute__((ext_vector_type(8)));

__device__ __forceinline__ float wsum(float v){
  #pragma unroll
  for(int o=32;o;o>>=1) v += __shfl_xor(v,o);
  return v;
}
__device__ __forceinline__ float wmax(float v){
  #pragma unroll
  for(int o=32;o;o>>=1) v = fmaxf(v,__shfl_xor(v,o));
  return v;
}
__device__ __forceinline__ u16 f2bf(float f){
  unsigned int u = __float_as_uint(f);
  u = (u + 0x7FFFu + ((u>>16)&1u)) >> 16;
  return (u16)u;
}
__device__ __forceinline__ float bf2f(u16 h){
  return __uint_as_float(((unsigned int)h)<<16);
}

// k1: blocks 0..127 = kB-self (xe/xa recomputed from xin; er2 bf16 [bi][s][16j]);
//     blocks 128..1151 = kA-lite (Sv/SSv + bf16 packs; W2 pack on 128..143).
__global__ void __launch_bounds__(256) k1(
    const float* __restrict__ xin, const float* __restrict__ pxp,
    const float* __restrict__ W2,  const float* __restrict__ sw,
    const float* __restrict__ bs,  const float* __restrict__ om,
    const float* __restrict__ tau, const float* __restrict__ temp,
    float* __restrict__ Sv, float* __restrict__ SSv,
    u16* __restrict__ xinb, u16* __restrict__ phi, u16* __restrict__ plo,
    u16* __restrict__ w2B,
    u16* __restrict__ er2b, float* __restrict__ mask, float* __restrict__ cc){
  __shared__ float shmF[1172];   // swL 1072 | bsL 16 | omL 16 | red 4 | redE 64
  int tid = threadIdx.x;
  if(blockIdx.x < 128){
    // ---- kB body (xe/xa self-computed) ----
    float* swL = shmF;
    float* bsL = swL + 1072;
    float* omL = bsL + 16;
    float* red = omL + 16;
    float* redE= red + 4;              // [16][4]
    int bi = blockIdx.x;               // (b*16+i)
    int i = bi & 15;
    int w = tid>>6, lane = tid&63;
    for(int k=tid;k<16*67;k+=256) swL[k] = sw[i*16*67 + k];
    if(tid<16){ bsL[tid]=bs[i*16+tid]; omL[tid]=fabsf(om[i*16+tid]); }
    float xs=0.f, xas=0.f;
    {
      const float4* xr = (const float4*)(xin + ((size_t)bi*256 + tid)*64);
      #pragma unroll
      for(int k=0;k<16;k++){
        float4 v4 = xr[k];
        xs  += v4.x+v4.y+v4.z+v4.w;
        xas += fabsf(v4.x)+fabsf(v4.y)+fabsf(v4.z)+fabsf(v4.w);
      }
    }
    float v   = xs *(1.f/64.f);
    float xav = xas*(1.f/64.f);
    float m = wmax(fabsf(v));
    if(lane==0) red[w]=m;
    __syncthreads();
    m = fmaxf(fmaxf(red[0],red[1]),fmaxf(red[2],red[3]));
    float xn = v/(m+1e-8f);
    xn = fminf(fmaxf(xn,-0.99f),0.99f);
    float sil = xn/(1.f+expf(-xn));
    float vv = (xn+1.f)*33.f;
    int c0 = (int)floorf(vv)-1;
    float acc[16];
    #pragma unroll
    for(int j=0;j<16;j++) acc[j]=0.f;
    #pragma unroll
    for(int k=0;k<4;k++){
      int c = c0+k;
      if(c<0||c>66) continue;
      float d = fabsf(vv-(float)c);
      float bas = d<1.f ? (2.f/3.f - d*d + d*d*d*0.5f)
                : (d<2.f ? (2.f-d)*(2.f-d)*(2.f-d)*(1.f/6.f) : 0.f);
      #pragma unroll
      for(int j=0;j<16;j++) acc[j] += bas*swL[j*67+c];
    }
    u16 evb[16];
    #pragma unroll
    for(int j=0;j<16;j++){
      float ev = sil*bsL[j] + acc[j] + omL[j];
      evb[j] = f2bf(ev);
      float pe = wsum(fabsf(ev)*xav);
      if(lane==0) redE[j*4+w]=pe;
    }
    *(u16x8*)(er2b + ((size_t)bi*256+tid)*16    ) = *(u16x8*)&evb[0];
    *(u16x8*)(er2b + ((size_t)bi*256+tid)*16 + 8) = *(u16x8*)&evb[8];
    __syncthreads();
    if(tid<16){
      float e = (redE[tid*4+0]+redE[tid*4+1]+redE[tid*4+2]+redE[tid*4+3])*(1.f/256.f);
      float tv = fabsf(temp[0])+1e-4f;
      float ta = fabsf(tau[i*16+tid]);
      float mk = 1.f/(1.f+expf(-(e-ta)/tv));
      mask[bi*16+tid]=mk;
      cc[bi*16+tid]= e/(ta+1e-8f)*mk;
    }
  } else {
    // ---- kA-lite body ----
    int ab = blockIdx.x - 128;
    int rl = tid>>3, q = tid&7;
    int row = ab*32 + rl;
    const float4* xr = (const float4*)(xin + row*64 + q*8);
    const float4* pr = (const float4*)(pxp + row*64 + q*8);
    float s3=0.f,s4=0.f;
    u16x8 xb, ph, pl;
    #pragma unroll
    for(int k=0;k<2;k++){
      float4 xv = xr[k];
      float4 pv = pr[k];
      s3 += pv.x+pv.y+pv.z+pv.w;
      s4 += pv.x*pv.x+pv.y*pv.y+pv.z*pv.z+pv.w*pv.w;
      int o = k*4;
      xb[o+0]=f2bf(xv.x); xb[o+1]=f2bf(xv.y); xb[o+2]=f2bf(xv.z); xb[o+3]=f2bf(xv.w);
      u16 h0=f2bf(pv.x), h1=f2bf(pv.y), h2=f2bf(pv.z), h3=f2bf(pv.w);
      ph[o+0]=h0; ph[o+1]=h1; ph[o+2]=h2; ph[o+3]=h3;
      pl[o+0]=f2bf(pv.x-bf2f(h0)); pl[o+1]=f2bf(pv.y-bf2f(h1));
      pl[o+2]=f2bf(pv.z-bf2f(h2)); pl[o+3]=f2bf(pv.w-bf2f(h3));
    }
    *(u16x8*)(xinb + row*64 + q*8) = xb;
    *(u16x8*)(phi  + row*64 + q*8) = ph;
    *(u16x8*)(plo  + row*64 + q*8) = pl;
    s3 += __shfl_xor(s3,1); s3 += __shfl_xor(s3,2); s3 += __shfl_xor(s3,4);
    s4 += __shfl_xor(s4,1); s4 += __shfl_xor(s4,2); s4 += __shfl_xor(s4,4);
    if(q==0){ Sv[row]=s3; SSv[row]=s4; }
    if(ab<16){
      int j = ab;
      for(int idx=tid; idx<4096; idx+=256){
        int f = idx>>6, o = idx&63;
        float vw = W2[j*4096 + idx];
        int ks = f>>5, kb = (f>>3)&3, ii = f&7;
        int nt = o>>4, col = o&15;
        int ln = kb*16 + col;
        w2B[((j*2+ks)*4 + nt)*512 + ln*8 + ii] = f2bf(vw);
      }
    }
  }
}

// k2: blocks 0..1023 = E2 gram MFMA (B staged in 16KB LDS, A direct from
//     global — wave-private contiguous panels); blocks 1024..2047 = kD-2j
//     (no longer LDS-capped); blocks 2048..2175 = LN stats. 16KB LDS union.
__global__ void __launch_bounds__(256) k2(
    const u16* __restrict__ phi, const u16* __restrict__ plo, float* __restrict__ G,
    const u16* __restrict__ xinb, const u16* __restrict__ er2b,
    const float* __restrict__ mask, const u16* __restrict__ w2B,
    const float* __restrict__ lnw, const float* __restrict__ lnb,
    const float* __restrict__ bp,
    u16* __restrict__ xvb, float* __restrict__ xp, u16* __restrict__ xpB,
    const float* __restrict__ Sv, const float* __restrict__ SSv,
    const float* __restrict__ cc,
    float* __restrict__ mKv, float* __restrict__ rKv,
    float* __restrict__ mQv, float* __restrict__ rQv){
  __shared__ __align__(16) unsigned char shm[16512];
  int tid = threadIdx.x;
  int bid = blockIdx.x;
  if(bid < 1024){
    // ---- E2 body: B staged (LDS 16KB), A direct ----
    u16* BfB = (u16*)shm;    // [2][4][2][64][8] = 8192 u16
    int e = bid;
    int b = e&7, m = (e>>3)&7, sx = (e>>6)&3, ty = e>>8;  // b lowest -> XCD=b
    int bm = b*8+m;
    int s0 = sx*64, t0 = ty*64;
    int row = tid>>2, dseg = tid&3;
    size_t offB = ((size_t)(b*16+m+8)*256 + t0 + row)*64 + dseg*16;
    int d0 = dseg*16;
    int ks0 = d0>>5, kb0 = (d0>>3)&3;
    int ks1 = (d0+8)>>5, kb1 = ((d0+8)>>3)&3;
    int lr0 = row&15, stile = row>>4;
    #define AOFF(h,stl,ks,ln) (((((h)*4+(stl))*2+(ks))*64 + (ln))*8)
    {
      uint4 x0 = *(const uint4*)(phi + offB);
      uint4 x1 = *(const uint4*)(phi + offB + 8);
      *(uint4*)(BfB + AOFF(0,stile,ks0,kb0*16+lr0)) = x0;
      *(uint4*)(BfB + AOFF(0,stile,ks1,kb1*16+lr0)) = x1;
      uint4 y0 = *(const uint4*)(plo + offB);
      uint4 y1 = *(const uint4*)(plo + offB + 8);
      *(uint4*)(BfB + AOFF(1,stile,ks0,kb0*16+lr0)) = y0;
      *(uint4*)(BfB + AOFF(1,stile,ks1,kb1*16+lr0)) = y1;
    }
    int w = tid>>6, lane = tid&63;
    int lr = lane&15, hk = lane>>4;
    size_t aoff = ((size_t)(b*16+m)*256 + s0 + w*16 + lr)*64 + hk*8;
    bf16x8 ah0 = *(const bf16x8*)(phi + aoff);        // ks=0
    bf16x8 ah1 = *(const bf16x8*)(phi + aoff + 32);   // ks=1
    bf16x8 al0 = *(const bf16x8*)(plo + aoff);
    bf16x8 al1 = *(const bf16x8*)(plo + aoff + 32);
    __syncthreads();
    f32x4 acc[4];
    #pragma unroll
    for(int tt=0;tt<4;tt++) acc[tt] = (f32x4){0.f,0.f,0.f,0.f};
    #pragma unroll
    for(int tt=0;tt<4;tt++){
      bf16x8 bh0 = *(const bf16x8*)(BfB + AOFF(0,tt,0,lane));
      bf16x8 bh1 = *(const bf16x8*)(BfB + AOFF(0,tt,1,lane));
      bf16x8 bl0 = *(const bf16x8*)(BfB + AOFF(1,tt,0,lane));
      bf16x8 bl1 = *(const bf16x8*)(BfB + AOFF(1,tt,1,lane));
      acc[tt] = __builtin_amdgcn_mfma_f32_16x16x32_bf16(ah0, bh0, acc[tt], 0,0,0);
      acc[tt] = __builtin_amdgcn_mfma_f32_16x16x32_bf16(ah1, bh1, acc[tt], 0,0,0);
      acc[tt] = __builtin_amdgcn_mfma_f32_16x16x32_bf16(ah0, bl0, acc[tt], 0,0,0);
      acc[tt] = __builtin_amdgcn_mfma_f32_16x16x32_bf16(ah1, bl1, acc[tt], 0,0,0);
      acc[tt] = __builtin_amdgcn_mfma_f32_16x16x32_bf16(al0, bh0, acc[tt], 0,0,0);
      acc[tt] = __builtin_amdgcn_mfma_f32_16x16x32_bf16(al1, bh1, acc[tt], 0,0,0);
    }
    int col = lane&15, r4 = lane>>4;
    #pragma unroll
    for(int tt=0;tt<4;tt++){
      #pragma unroll
      for(int r=0;r<4;r++){
        G[((size_t)bm*256 + s0 + w*16 + r4*4 + r)*256 + t0 + tt*16 + col] = acc[tt][r];
      }
    }
    #undef AOFF
  } else if(bid < 2048){
    // ---- kD-2j body ----
    int idx = bid - 1024;               // 1024%8==0 -> XCD = b preserved
    int b = idx&7, jq = (idx>>3)&7, st = idx>>6;
    int j0 = jq*2;
    int w = tid>>6, lane = tid&63;
    u16* xnS = (u16*)shm;               // [2][1024] u16
    float* mcL = (float*)(shm + 4096);  // [32]
    if(tid<32) mcL[tid] = mask[(b*16+(tid>>1))*16 + j0 + (tid&1)];
    __syncthreads();
    int ss = lane>>4, fq = lane&15;
    int sl = w*4 + ss;
    int s  = st*16 + sl;
    float a00=0.f,a01=0.f,a02=0.f,a03=0.f;
    float a10=0.f,a11=0.f,a12=0.f,a13=0.f;
    #pragma unroll
    for(int i=0;i<16;i++){
      unsigned int epk = *(const unsigned int*)(er2b + ((size_t)((b*16+i)*256+s))*16 + j0);
      float e0 = bf2f((u16)(epk&0xFFFFu))*mcL[i*2+0];
      float e1 = bf2f((u16)(epk>>16))   *mcL[i*2+1];
      ushort4 xv = *(const ushort4*)(xinb + ((size_t)(b*16+i)*256+s)*64 + fq*4);
      float x0=bf2f(xv.x), x1=bf2f(xv.y), x2=bf2f(xv.z), x3=bf2f(xv.w);
      a00 += e0*x0; a01 += e0*x1; a02 += e0*x2; a03 += e0*x3;
      a10 += e1*x0; a11 += e1*x1; a12 += e1*x2; a13 += e1*x3;
    }
    #pragma unroll
    for(int jj=0;jj<2;jj++){
      int j = j0+jj;
      int bj = b*16+j;
      float acc0 = (jj? a10:a00)*(1.f/16.f);
      float acc1 = (jj? a11:a01)*(1.f/16.f);
      float acc2 = (jj? a12:a02)*(1.f/16.f);
      float acc3 = (jj? a13:a03)*(1.f/16.f);
      {
        u16 pk[4]={f2bf(acc0),f2bf(acc1),f2bf(acc2),f2bf(acc3)};
        *(ushort4*)(xvb + ((size_t)bj*256+s)*64 + fq*4) = *(ushort4*)pk;
      }
      float part = acc0+acc1+acc2+acc3;
      part += __shfl_xor(part,1); part += __shfl_xor(part,2);
      part += __shfl_xor(part,4); part += __shfl_xor(part,8);
      float mu = part*(1.f/64.f);
      float d0=acc0-mu, d1=acc1-mu, d2=acc2-mu, d3=acc3-mu;
      float p2 = d0*d0+d1*d1+d2*d2+d3*d3;
      p2 += __shfl_xor(p2,1); p2 += __shfl_xor(p2,2);
      p2 += __shfl_xor(p2,4); p2 += __shfl_xor(p2,8);
      float rstd = rsqrtf(p2*(1.f/64.f)+EPSLN);
      float4 lw4 = *(const float4*)(lnw + j*64 + fq*4);
      float4 lb4 = *(const float4*)(lnb + j*64 + fq*4);
      u16 xn[4] = { f2bf(d0*rstd*lw4.x + lb4.x), f2bf(d1*rstd*lw4.y + lb4.y),
                    f2bf(d2*rstd*lw4.z + lb4.z), f2bf(d3*rstd*lw4.w + lb4.w) };
      *(ushort4*)((unsigned char*)(xnS + jj*1024) + ((sl*128 + fq*8) ^ ((sl&7)<<4))) = *(ushort4*)xn;
    }
    __syncthreads();
    int m = lane&15, kb = lane>>4;
    #pragma unroll
    for(int jj=0;jj<2;jj++){
      int j = j0+jj;
      int bj = b*16+j;
      f32x4 acc = {0.f,0.f,0.f,0.f};
      unsigned char* xnB = (unsigned char*)(xnS + jj*1024);
      #pragma unroll
      for(int ks=0;ks<2;ks++){
        bf16x8 a = *(const bf16x8*)(xnB + ((m*128 + ks*64 + kb*16) ^ ((m&7)<<4)));
        bf16x8 bfr = *(const bf16x8*)(w2B + ((j*2+ks)*4 + w)*512 + lane*8);
        acc = __builtin_amdgcn_mfma_f32_16x16x32_bf16(a, bfr, acc, 0, 0, 0);
      }
      int f = w*16 + m;
      u16 pk[4];
      #pragma unroll
      for(int r=0;r<4;r++){
        int si = kb*4 + r;
        int s2 = st*16 + si;
        float xpr = acc[r] + bp[((size_t)j*256+s2)*64+f];
        xp[((size_t)bj*256+s2)*64+f] = xpr;
        pk[r] = f2bf(xpr);
      }
      int s0 = st*16 + kb*4;
      int flat = ((s0>>5)*4 + w)*512 + ((s0>>3)&3)*128 + m*8 + (s0&7);
      *(ushort4*)(xpB + (size_t)bj*16384 + flat) = *(ushort4*)pk;
    }
  } else {
    // ---- LN stats for (b,j): closed form from Sv/SSv ----
    int sid = bid - 2048;
    int b = sid&7, j = sid>>3;
    int t = tid;
    float sk=0,ssk=0,sq=0,ssq=0;
    #pragma unroll
    for(int m=0;m<8;m++){
      float ck = cc[(b*16+m)*16+j];
      float cq = cc[(b*16+m+8)*16+j];
      sk  += ck*Sv[(b*16+m)*256+t];
      ssk += ck*ck*SSv[(b*16+m)*256+t];
      sq  += cq*Sv[(b*16+m+8)*256+t];
      ssq += cq*cq*SSv[(b*16+m+8)*256+t];
    }
    float mk = sk*(1.f/512.f);
    float vk = ssk*(1.f/512.f) - mk*mk;
    float mq = sq*(1.f/512.f);
    float vq = ssq*(1.f/512.f) - mq*mq;
    int o = (b*16+j)*256+t;
    mKv[o]=mk; rKv[o]=rsqrtf(vk+EPSLN);
    mQv[o]=mq; rQv[o]=rsqrtf(vq+EPSLN);
  }
}

// F v4: stats precomputed; 4 j per block, 2 prob panels; LDS 25.5KB.
__global__ void __launch_bounds__(256) kF(
    const float* __restrict__ G, const float* __restrict__ cc,
    const float* __restrict__ mKv, const float* __restrict__ rKv,
    const float* __restrict__ mQv, const float* __restrict__ rQv,
    const float* __restrict__ xp, const u16* __restrict__ xpB,
    const float* __restrict__ cw,
    const u16* __restrict__ xarrb, const float* __restrict__ temp,
    const float* __restrict__ alpha, const float* __restrict__ beta,
    const float* __restrict__ gamma_, const float* __restrict__ theta,
    float* __restrict__ out){
  int b = blockIdx.x, jp = blockIdx.y, st = blockIdx.z;
  int j0 = jp*4;
  int tid = threadIdx.x, w = tid>>6, lane = tid&63;
  __shared__ __align__(16) unsigned char ovl[26112];
  unsigned char* prA = ovl;
  unsigned char* prB = ovl + 8192;
  float* xpT = (float*)ovl;
  float tv = fabsf(temp[0])+1e-4f;
  float inv = 1.f/(sqrtf(512.f)*tv);
  float aM0[8],aM1[8],aM2[8],aM3[8];
  #pragma unroll
  for(int m=0;m<8;m++){
    float4 ck = *(const float4*)(cc + (b*16+m  )*16 + j0);
    float4 cq = *(const float4*)(cc + (b*16+m+8)*16 + j0);
    aM0[m]=ck.x*cq.x; aM1[m]=ck.y*cq.y; aM2[m]=ck.z*cq.z; aM3[m]=ck.w*cq.w;
  }
  int bj0 = b*16+j0;
  float4 mQ4a = *(const float4*)(mQv + (size_t)(bj0  )*256 + lane*4);
  float4 rQ4a = *(const float4*)(rQv + (size_t)(bj0  )*256 + lane*4);
  float4 mQ4b = *(const float4*)(mQv + (size_t)(bj0+1)*256 + lane*4);
  float4 rQ4b = *(const float4*)(rQv + (size_t)(bj0+1)*256 + lane*4);
  float4 mQ4c = *(const float4*)(mQv + (size_t)(bj0+2)*256 + lane*4);
  float4 rQ4c = *(const float4*)(rQv + (size_t)(bj0+2)*256 + lane*4);
  float4 mQ4d = *(const float4*)(mQv + (size_t)(bj0+3)*256 + lane*4);
  float4 rQ4d = *(const float4*)(rQv + (size_t)(bj0+3)*256 + lane*4);
  const float* Gb = G + (size_t)(b*8)*65536;
  ushort4 pk2[4], pk3[4];   // j2/j3 probs held in registers
  #pragma unroll
  for(int q=0;q<4;q++){
    int si = w*4+q;
    int s = st*16 + si;
    f32x4 dt0={0.f,0.f,0.f,0.f}, dt1={0.f,0.f,0.f,0.f};
    f32x4 dt2={0.f,0.f,0.f,0.f}, dt3={0.f,0.f,0.f,0.f};
    #pragma unroll
    for(int m=0;m<8;m++){
      f32x4 g4 = *(const f32x4*)(Gb + (size_t)m*65536 + s*256 + lane*4);
      dt0 += aM0[m]*g4; dt1 += aM1[m]*g4;
      dt2 += aM2[m]*g4; dt3 += aM3[m]*g4;
    }
    // defer-max: LN'd rows => |raw| <= sqrt(512)/tv ~ 22.6, exp safe without max-sub
    #define SMK(JJ, DT, MQ, RQ, PKOUT) { \
      float mKs = 512.f*mKv[(size_t)(bj0+JJ)*256 + s], rKs = rKv[(size_t)(bj0+JJ)*256 + s]; \
      float e0 = __expf((DT[0] - mKs*MQ.x)*rKs*RQ.x*inv); \
      float e1 = __expf((DT[1] - mKs*MQ.y)*rKs*RQ.y*inv); \
      float e2 = __expf((DT[2] - mKs*MQ.z)*rKs*RQ.z*inv); \
      float e3 = __expf((DT[3] - mKs*MQ.w)*rKs*RQ.w*inv); \
      float isf = 1.f/wsum(e0+e1+e2+e3); \
      u16 pk[4] = {f2bf(e0*isf), f2bf(e1*isf), f2bf(e2*isf), f2bf(e3*isf)}; \
      PKOUT = *(ushort4*)pk; }
    ushort4 t0v, t1v;
    SMK(0, dt0, mQ4a, rQ4a, t0v)
    SMK(1, dt1, mQ4b, rQ4b, t1v)
    int poff = (si*512 + lane*8) ^ ((si&7)<<4);
    *(ushort4*)(prA + poff) = t0v;
    *(ushort4*)(prB + poff) = t1v;
    SMK(2, dt2, mQ4c, rQ4c, pk2[q])
    SMK(3, dt3, mQ4d, rQ4d, pk3[q])
    #undef SMK
  }
  __syncthreads();
  int m_ = lane&15, kb = lane>>4;
  f32x4 av0={0.f,0.f,0.f,0.f}, av1={0.f,0.f,0.f,0.f};
  f32x4 av2={0.f,0.f,0.f,0.f}, av3={0.f,0.f,0.f,0.f};
  const u16* xpB0 = xpB + (size_t)(bj0  )*16384;
  const u16* xpB1 = xpB + (size_t)(bj0+1)*16384;
  const u16* xpB2 = xpB + (size_t)(bj0+2)*16384;
  const u16* xpB3 = xpB + (size_t)(bj0+3)*16384;
  #pragma unroll
  for(int ks=0;ks<8;ks++){
    int aoff = (m_*512 + ks*64 + kb*16) ^ ((m_&7)<<4);
    int boff = ((ks*4 + w)*64 + lane)*8;
    bf16x8 a0 = *(const bf16x8*)(prA + aoff);
    bf16x8 a1 = *(const bf16x8*)(prB + aoff);
    av0 = __builtin_amdgcn_mfma_f32_16x16x32_bf16(a0, *(const bf16x8*)(xpB0 + boff), av0, 0,0,0);
    av1 = __builtin_amdgcn_mfma_f32_16x16x32_bf16(a1, *(const bf16x8*)(xpB1 + boff), av1, 0,0,0);
  }
  __syncthreads();   // AV(j0,j1) prob reads done -> panels reusable
  #pragma unroll
  for(int q=0;q<4;q++){
    int si = w*4+q;
    int poff = (si*512 + lane*8) ^ ((si&7)<<4);
    *(ushort4*)(prA + poff) = pk2[q];
    *(ushort4*)(prB + poff) = pk3[q];
  }
  __syncthreads();
  #pragma unroll
  for(int ks=0;ks<8;ks++){
    int aoff = (m_*512 + ks*64 + kb*16) ^ ((m_&7)<<4);
    int boff = ((ks*4 + w)*64 + lane)*8;
    bf16x8 a2 = *(const bf16x8*)(prA + aoff);
    bf16x8 a3 = *(const bf16x8*)(prB + aoff);
    av2 = __builtin_amdgcn_mfma_f32_16x16x32_bf16(a2, *(const bf16x8*)(xpB2 + boff), av2, 0,0,0);
    av3 = __builtin_amdgcn_mfma_f32_16x16x32_bf16(a3, *(const bf16x8*)(xpB3 + boff), av3, 0,0,0);
  }
  int f = w*16 + m_;
  #pragma unroll
  for(int pass=0; pass<2; pass++){
    __syncthreads();   // previous ovl readers done (probs or pass-0 xpT)
    for(int idx4 = tid; idx4 < 1536; idx4 += 256){
      int jj = idx4 / 768;
      int rem = idx4 - jj*768;
      int rr_i = rem >> 8;
      int pos = rem & 255;
      int ci = pos>>4, f4 = pos&15;
      int grow = st - 1 + rr_i;
      float4 v = {0.f,0.f,0.f,0.f};
      if(grow>=0 && grow<16){
        v = *(const float4*)(xp + ((size_t)(b*16+j0+pass*2+jj)*256 + grow*16 + ci)*64 + f4*4);
      }
      *(float4*)(xpT + ((jj*3+rr_i)*16+ci)*68 + f4*4) = v;
    }
    __syncthreads();
    #pragma unroll
    for(int jj=0;jj<2;jj++){
      int j = j0 + pass*2 + jj;
      int bj = b*16+j;
      f32x4 acc = pass==0 ? (jj?av1:av0) : (jj?av3:av2);
      float al = fabsf(alpha[j]), be=fabsf(beta[j]), th=fabsf(theta[j]), ga=gamma_[j];
      const float* wq = cw + (j*64+f)*9;
      float w0=wq[0],w1=wq[1],w2=wq[2],w3v=wq[3],w4=wq[4],w5=wq[5],w6=wq[6],w7=wq[7],w8=wq[8];
      #pragma unroll
      for(int r=0;r<4;r++){
        int si = kb*4 + r;
        int s = st*16 + si;
        float gl = acc[r];
        float cv=0.f;
        #pragma unroll
        for(int dr=0;dr<3;dr++){
          float kw0 = dr==0?w0:(dr==1?w3v:w6);
          float kw1 = dr==0?w1:(dr==1?w4:w7);
          float kw2 = dr==0?w2:(dr==1?w5:w8);
          const float* rowp = xpT + ((jj*3+dr)*16)*68;
          if(si>0)  cv += rowp[(si-1)*68+f]*kw0;
                    cv += rowp[(si  )*68+f]*kw1;
          if(si<15) cv += rowp[(si+1)*68+f]*kw2;
        }
        float diag = xpT[((jj*3+1)*16+si)*68+f];
        size_t gi = ((size_t)bj*256+s)*64+f;
        out[gi] = be*gl + al*diag + th*cv + ga*bf2f(xarrb[gi]);
      }
    }
  }
}

extern "C" void kernel_launch(void* const* d_in, const int* in_sizes, int n_in,
                              void* d_out, int out_size, void* d_ws, size_t ws_size,
                              hipStream_t stream) {
  const float* xin = (const float*)d_in[0];
  const float* pxp = (const float*)d_in[1];
  const float* sw  = (const float*)d_in[2];
  const float* bs  = (const float*)d_in[3];
  const float* tau = (const float*)d_in[4];
  const float* temp= (const float*)d_in[5];
  const float* om  = (const float*)d_in[6];
  const float* W2  = (const float*)d_in[7];
  const float* bp  = (const float*)d_in[8];
  const float* lnw = (const float*)d_in[9];
  const float* lnb = (const float*)d_in[10];
  const float* alpha=(const float*)d_in[11];
  const float* beta= (const float*)d_in[12];
  const float* gam = (const float*)d_in[13];
  const float* theta=(const float*)d_in[14];
  const float* cw  = (const float*)d_in[15];
  float* outp = (float*)d_out;
  float* xpo  = outp + 2097152;   // x_prime = second output

  float* ws  = (float*)d_ws;
  float* Sv  = ws;                // 32768
  float* SSv = Sv + 32768;        // 32768
  u16*   er2b= (u16*)(SSv + 32768);   // 524288 u16, layout [bi][s][16 j]
  float* mask= (float*)(er2b) + 524288;
  float* ccv = mask + 2048;       // 2048
  float* mKv = ccv + 2048;        // 32768
  float* rKv = mKv + 32768;       // 32768
  float* mQv = rKv + 32768;       // 32768
  float* rQv = mQv + 32768;       // 32768
  float* Gv  = rQv + 32768;       // 4194304
  u16* xvb = (u16*)(Gv + 4194304);    // 2097152 u16 (bf16 x)
  u16* xpB = xvb + 2097152;           // 2097152 u16
  u16* w2B = xpB + 2097152;           // 65536 u16
  u16* xinb= w2B + 65536;             // 2097152 u16
  u16* phi = xinb + 2097152;          // 2097152 u16
  u16* plo = phi + 2097152;           // 2097152 u16

  k1<<<1152,256,0,stream>>>(xin,pxp,W2,sw,bs,om,tau,temp,
                            Sv,SSv,xinb,phi,plo,w2B,er2b,mask,ccv);
  k2<<<2176,256,0,stream>>>(phi,plo,Gv,xinb,er2b,mask,w2B,lnw,lnb,bp,
                            xvb,xpo,xpB,Sv,SSv,ccv,mKv,rKv,mQv,rQv);
  kF<<<dim3(8,4,16),256,0,stream>>>(Gv,ccv,mKv,rKv,mQv,rQv,xpo,xpB,cw,xvb,temp,
                                    alpha,beta,gam,theta,outp);
}